// Round 1
// baseline (598.053 us; speedup 1.0000x reference)
//
#include <hip/hip_runtime.h>
#include <hip/hip_bf16.h>

// GCN 3-layer: h = relu(gcn(x,W1,b1)); h = relu(gcn(h,W2,b2)); out = gcn(h,W3,b3)
// gcn(x,W,b): g = (x@W)*dis[row]; out[i] = dis[i]*(g[i] + sum_{in-edges} g[src]) + b
// dis[i] = rsqrt(1 + indegree[i]) (self-loop included)

// ---------------- graph preprocessing ----------------

__global__ void zero_kernel(int* __restrict__ p, int n) {
    int i = blockIdx.x * blockDim.x + threadIdx.x;
    if (i < n) p[i] = 0;
}

__global__ void count_kernel(const int* __restrict__ dst, int* __restrict__ count, int e) {
    int i = blockIdx.x * blockDim.x + threadIdx.x;
    if (i < e) atomicAdd(&count[dst[i]], 1);
}

__global__ void dis_kernel(const int* __restrict__ count, float* __restrict__ dis, int n) {
    int i = blockIdx.x * blockDim.x + threadIdx.x;
    if (i < n) dis[i] = rsqrtf((float)(count[i] + 1));
}

// single-block exclusive scan over count[0..n) -> offsets/cursor; offsets[n] = total
__global__ __launch_bounds__(1024) void scan_kernel(const int* __restrict__ count,
                                                    int* __restrict__ offsets,
                                                    int* __restrict__ cursor, int n) {
    __shared__ int wsum[16];
    __shared__ int s_running;
    int tid = threadIdx.x;
    int lane = tid & 63, wid = tid >> 6;
    if (tid == 0) s_running = 0;
    __syncthreads();
    for (int base = 0; base < n; base += 1024) {
        int i = base + tid;
        int v = (i < n) ? count[i] : 0;
        int x = v;
        #pragma unroll
        for (int d = 1; d < 64; d <<= 1) {
            int t = __shfl_up(x, d, 64);
            if (lane >= d) x += t;
        }
        if (lane == 63) wsum[wid] = x;
        __syncthreads();
        if (wid == 0) {
            int wv = (lane < 16) ? wsum[lane] : 0;
            #pragma unroll
            for (int d = 1; d < 16; d <<= 1) {
                int t = __shfl_up(wv, d, 64);
                if (lane >= d) wv += t;
            }
            if (lane < 16) wsum[lane] = wv;  // inclusive scan of wave sums
        }
        __syncthreads();
        int waveExcl = (wid == 0) ? 0 : wsum[wid - 1];
        int excl = s_running + waveExcl + (x - v);
        if (i < n) { offsets[i] = excl; cursor[i] = excl; }
        __syncthreads();
        if (tid == 1023) s_running += wsum[15];
        __syncthreads();
    }
    if (tid == 0) offsets[n] = s_running;
}

__global__ void fill_kernel(const int* __restrict__ src, const int* __restrict__ dst,
                            int* __restrict__ cursor, int* __restrict__ srcs_sorted, int e) {
    int i = blockIdx.x * blockDim.x + threadIdx.x;
    if (i < e) {
        int d = dst[i];
        int pos = atomicAdd(&cursor[d], 1);
        srcs_sorted[pos] = src[i];
    }
}

// ---------------- GEMM: g[row][c] = dis[row] * sum_k in[row][k]*W[k][c] ----------------

template<int CIN, int COUT, int ROWS>
__global__ __launch_bounds__(256) void gemm_scale(const float* __restrict__ in,
                                                  const float* __restrict__ W,
                                                  const float* __restrict__ dis,
                                                  float* __restrict__ out, int n) {
    __shared__ float wlds[CIN * COUT];
    for (int i = threadIdx.x; i < CIN * COUT; i += 256) wlds[i] = W[i];
    __syncthreads();
    constexpr int RPP = 256 / COUT;  // rows per pass
    int c = threadIdx.x % COUT;
    int r0 = threadIdx.x / COUT;
    int rowBase = blockIdx.x * ROWS;
    for (int rr = r0; rr < ROWS; rr += RPP) {
        int row = rowBase + rr;
        if (row >= n) continue;
        const float* inr = in + (size_t)row * CIN;
        float sum = 0.f;
        #pragma unroll
        for (int k = 0; k < CIN; k += 4) {
            float4 a = *reinterpret_cast<const float4*>(inr + k);
            sum += a.x * wlds[(k + 0) * COUT + c];
            sum += a.y * wlds[(k + 1) * COUT + c];
            sum += a.z * wlds[(k + 2) * COUT + c];
            sum += a.w * wlds[(k + 3) * COUT + c];
        }
        out[(size_t)row * COUT + c] = sum * dis[row];
    }
}

// ---------------- aggregate: out[i][c] = [relu](dis[i]*(g[i][c] + sum g[src][c]) + b[c]) ----------------

template<int C, bool RELU>
__global__ __launch_bounds__(C) void aggregate(const float* __restrict__ g,
                                               const int* __restrict__ srcs,
                                               const int* __restrict__ offsets,
                                               const float* __restrict__ dis,
                                               const float* __restrict__ bias,
                                               float* __restrict__ out, int n) {
    int i = blockIdx.x;
    if (i >= n) return;
    int c = threadIdx.x;
    float acc = g[(size_t)i * C + c];
    int e0 = offsets[i], e1 = offsets[i + 1];
    for (int e = e0; e < e1; ++e) {
        int s = srcs[e];
        acc += g[(size_t)s * C + c];
    }
    float v = dis[i] * acc + bias[c];
    if (RELU) v = fmaxf(v, 0.f);
    out[(size_t)i * C + c] = v;
}

// ---------------- launch ----------------

extern "C" void kernel_launch(void* const* d_in, const int* in_sizes, int n_in,
                              void* d_out, int out_size, void* d_ws, size_t ws_size,
                              hipStream_t stream) {
    const float* x  = (const float*)d_in[0];
    const int*   ei = (const int*)d_in[1];
    const float* W1 = (const float*)d_in[2];
    const float* b1 = (const float*)d_in[3];
    const float* W2 = (const float*)d_in[4];
    const float* b2 = (const float*)d_in[5];
    const float* W3 = (const float*)d_in[6];
    const float* b3 = (const float*)d_in[7];
    float* out = (float*)d_out;

    const int n = in_sizes[0] / 64;   // 50000
    const int e = in_sizes[1] / 2;    // 800000
    const int* src = ei;
    const int* dst = ei + e;

    // workspace layout (4-byte units)
    int*   ws_i = (int*)d_ws;
    float* ws_f = (float*)d_ws;
    size_t o = 0;
    int* count   = ws_i + o; o += n;
    int* offsets = ws_i + o; o += n + 8;
    int* cursor  = ws_i + o; o += n;
    int* srcs    = ws_i + o; o += e;
    float* dis   = ws_f + o; o += n;
    o = (o + 3) & ~(size_t)3;
    float* bufA  = ws_f + o; o += (size_t)n * 128;
    float* bufB  = ws_f + o; o += (size_t)n * 128;

    const int B = 256;
    // graph preprocessing (layer-invariant)
    zero_kernel<<<(n + B - 1) / B, B, 0, stream>>>(count, n);
    count_kernel<<<(e + B - 1) / B, B, 0, stream>>>(dst, count, e);
    dis_kernel<<<(n + B - 1) / B, B, 0, stream>>>(count, dis, n);
    scan_kernel<<<1, 1024, 0, stream>>>(count, offsets, cursor, n);
    fill_kernel<<<(e + B - 1) / B, B, 0, stream>>>(src, dst, cursor, srcs, e);

    const int ROWS = 16;
    dim3 ggrid((n + ROWS - 1) / ROWS);

    // layer 1: x[*,64] @ W1[64,128]
    gemm_scale<64, 128, ROWS><<<ggrid, 256, 0, stream>>>(x, W1, dis, bufA, n);
    aggregate<128, true><<<n, 128, 0, stream>>>(bufA, srcs, offsets, dis, b1, bufB, n);
    // layer 2: bufB[*,128] @ W2[128,128]
    gemm_scale<128, 128, ROWS><<<ggrid, 256, 0, stream>>>(bufB, W2, dis, bufA, n);
    aggregate<128, true><<<n, 128, 0, stream>>>(bufA, srcs, offsets, dis, b2, bufB, n);
    // layer 3: bufB[*,128] @ W3[128,64]
    gemm_scale<128, 64, ROWS><<<ggrid, 256, 0, stream>>>(bufB, W3, dis, bufA, n);
    aggregate<64, false><<<n, 64, 0, stream>>>(bufA, srcs, offsets, dis, b3, out, n);
}

// Round 2
// 404.643 us; speedup vs baseline: 1.4780x; 1.4780x over previous
//
#include <hip/hip_runtime.h>
#include <hip/hip_bf16.h>

// GCN 3-layer: h = relu(gcn(x,W1,b1)); h = relu(gcn(h,W2,b2)); out = gcn(h,W3,b3)
// gcn(x,W,b): g = (x@W)*dis[row]; out[i] = dis[i]*(g[i] + sum_{in-edges} g[src]) + b
// dis[i] = rsqrt(1 + indegree[i]) (self-loop included)

// ---------------- graph preprocessing ----------------

__global__ void zero_kernel(int* __restrict__ p, int n) {
    int i = blockIdx.x * blockDim.x + threadIdx.x;
    if (i < n) p[i] = 0;
}

__global__ void count_kernel(const int* __restrict__ dst, int* __restrict__ count, int e) {
    int i = blockIdx.x * blockDim.x + threadIdx.x;
    if (i < e) atomicAdd(&count[dst[i]], 1);
}

__global__ void dis_kernel(const int* __restrict__ count, float* __restrict__ dis, int n) {
    int i = blockIdx.x * blockDim.x + threadIdx.x;
    if (i < n) dis[i] = rsqrtf((float)(count[i] + 1));
}

// single-block exclusive scan: 1024 threads x 64 elements in registers, one block-scan pass
__global__ __launch_bounds__(1024) void scan_kernel(const int* __restrict__ count,
                                                    int* __restrict__ offsets,
                                                    int* __restrict__ cursor, int n) {
    constexpr int T = 64;  // elements per thread; covers n <= 65536
    __shared__ int wsum[16];
    int tid = threadIdx.x;
    int lane = tid & 63, wid = tid >> 6;
    int base = tid * T;

    int v[T];
    int tot = 0;
    if (base + T <= n) {
        #pragma unroll
        for (int j = 0; j < T; j += 4) {
            int4 c4 = *reinterpret_cast<const int4*>(count + base + j);
            v[j + 0] = tot; tot += c4.x;
            v[j + 1] = tot; tot += c4.y;
            v[j + 2] = tot; tot += c4.z;
            v[j + 3] = tot; tot += c4.w;
        }
    } else {
        #pragma unroll
        for (int j = 0; j < T; ++j) {
            int idx = base + j;
            int c = (idx < n) ? count[idx] : 0;
            v[j] = tot; tot += c;
        }
    }

    // inclusive wave-scan of per-thread totals
    int x = tot;
    #pragma unroll
    for (int d = 1; d < 64; d <<= 1) {
        int t = __shfl_up(x, d, 64);
        if (lane >= d) x += t;
    }
    if (lane == 63) wsum[wid] = x;
    __syncthreads();
    if (wid == 0 && lane < 16) {
        int wv = wsum[lane];
        #pragma unroll
        for (int d = 1; d < 16; d <<= 1) {
            int t = __shfl_up(wv, d, 64);
            if (lane >= d) wv += t;
        }
        wsum[lane] = wv;  // inclusive scan of wave sums
    }
    __syncthreads();
    int waveExcl = (wid == 0) ? 0 : wsum[wid - 1];
    int tbase = waveExcl + (x - tot);  // exclusive base for this thread

    if (base + T <= n) {
        #pragma unroll
        for (int j = 0; j < T; j += 4) {
            int4 o4 = make_int4(tbase + v[j], tbase + v[j + 1], tbase + v[j + 2], tbase + v[j + 3]);
            *reinterpret_cast<int4*>(offsets + base + j) = o4;
            *reinterpret_cast<int4*>(cursor + base + j) = o4;
        }
    } else {
        #pragma unroll
        for (int j = 0; j < T; ++j) {
            int idx = base + j;
            if (idx < n) { offsets[idx] = tbase + v[j]; cursor[idx] = tbase + v[j]; }
        }
    }
    if (tid == 1023) offsets[n] = tbase + tot;  // grand total
}

__global__ void fill_kernel(const int* __restrict__ src, const int* __restrict__ dst,
                            int* __restrict__ cursor, int* __restrict__ srcs_sorted, int e) {
    int i = blockIdx.x * blockDim.x + threadIdx.x;
    if (i < e) {
        int d = dst[i];
        int pos = atomicAdd(&cursor[d], 1);
        srcs_sorted[pos] = src[i];
    }
}

// ---------------- GEMM: g[row][c] = dis[row] * sum_k in[row][k]*W[k][c] ----------------
// 4x4 register tile per thread; W in LDS (b128 reads), input direct from global
// (same address across col-lanes -> broadcast, L1-served).

template<int CIN, int COUT>
__global__ __launch_bounds__(256) void gemm_scale(const float* __restrict__ in,
                                                  const float* __restrict__ W,
                                                  const float* __restrict__ dis,
                                                  float* __restrict__ out, int n) {
    constexpr int G = COUT / 4;      // col groups (threads across columns)
    constexpr int TY = 256 / G;      // row groups
    constexpr int R = TY * 4;        // rows per block
    __shared__ float wlds[CIN * COUT];
    for (int idx = threadIdx.x * 4; idx < CIN * COUT; idx += 1024)
        *reinterpret_cast<float4*>(&wlds[idx]) = *reinterpret_cast<const float4*>(&W[idx]);
    __syncthreads();

    int tx = threadIdx.x % G;
    int ty = threadIdx.x / G;
    int c0 = tx * 4;
    int rowBase = blockIdx.x * R + ty * 4;

    int r[4];
    #pragma unroll
    for (int i = 0; i < 4; ++i) r[i] = min(rowBase + i, n - 1);

    float4 acc[4];
    #pragma unroll
    for (int i = 0; i < 4; ++i) acc[i] = make_float4(0.f, 0.f, 0.f, 0.f);

    #pragma unroll 4
    for (int k = 0; k < CIN; k += 4) {
        float4 w0 = *reinterpret_cast<const float4*>(&wlds[(k + 0) * COUT + c0]);
        float4 w1 = *reinterpret_cast<const float4*>(&wlds[(k + 1) * COUT + c0]);
        float4 w2 = *reinterpret_cast<const float4*>(&wlds[(k + 2) * COUT + c0]);
        float4 w3 = *reinterpret_cast<const float4*>(&wlds[(k + 3) * COUT + c0]);
        #pragma unroll
        for (int i = 0; i < 4; ++i) {
            float4 a = *reinterpret_cast<const float4*>(in + (size_t)r[i] * CIN + k);
            acc[i].x += a.x * w0.x + a.y * w1.x + a.z * w2.x + a.w * w3.x;
            acc[i].y += a.x * w0.y + a.y * w1.y + a.z * w2.y + a.w * w3.y;
            acc[i].z += a.x * w0.z + a.y * w1.z + a.z * w2.z + a.w * w3.z;
            acc[i].w += a.x * w0.w + a.y * w1.w + a.z * w2.w + a.w * w3.w;
        }
    }

    #pragma unroll
    for (int i = 0; i < 4; ++i) {
        if (rowBase + i < n) {
            float d = dis[r[i]];
            float4 o = make_float4(acc[i].x * d, acc[i].y * d, acc[i].z * d, acc[i].w * d);
            *reinterpret_cast<float4*>(out + (size_t)r[i] * COUT + c0) = o;
        }
    }
}

// ---------------- aggregate: out[i][c] = [relu](dis[i]*(g[i][c] + sum g[src][c]) + b[c]) ----
// one wave per node; float2 lanes for C=128, float for C=64; edge loop unrolled x4.

template<int C, bool RELU>
__global__ __launch_bounds__(256) void aggregate(const float* __restrict__ g,
                                                 const int* __restrict__ srcs,
                                                 const int* __restrict__ offsets,
                                                 const float* __restrict__ dis,
                                                 const float* __restrict__ bias,
                                                 float* __restrict__ out, int n) {
    constexpr int VEC = C / 64;
    int wid = threadIdx.x >> 6, lane = threadIdx.x & 63;
    int i = blockIdx.x * 4 + wid;
    if (i >= n) return;
    int c = lane * VEC;

    float accx, accy = 0.f;
    if constexpr (VEC == 2) {
        float2 t = *reinterpret_cast<const float2*>(g + (size_t)i * C + c);
        accx = t.x; accy = t.y;
    } else {
        accx = g[(size_t)i * C + c];
    }

    int e0 = offsets[i], e1 = offsets[i + 1];
    int e = e0;
    for (; e + 4 <= e1; e += 4) {
        int s0 = srcs[e + 0], s1 = srcs[e + 1], s2 = srcs[e + 2], s3 = srcs[e + 3];
        if constexpr (VEC == 2) {
            float2 v0 = *reinterpret_cast<const float2*>(g + (size_t)s0 * C + c);
            float2 v1 = *reinterpret_cast<const float2*>(g + (size_t)s1 * C + c);
            float2 v2 = *reinterpret_cast<const float2*>(g + (size_t)s2 * C + c);
            float2 v3 = *reinterpret_cast<const float2*>(g + (size_t)s3 * C + c);
            accx += (v0.x + v1.x) + (v2.x + v3.x);
            accy += (v0.y + v1.y) + (v2.y + v3.y);
        } else {
            float v0 = g[(size_t)s0 * C + c];
            float v1 = g[(size_t)s1 * C + c];
            float v2 = g[(size_t)s2 * C + c];
            float v3 = g[(size_t)s3 * C + c];
            accx += (v0 + v1) + (v2 + v3);
        }
    }
    for (; e < e1; ++e) {
        int s = srcs[e];
        if constexpr (VEC == 2) {
            float2 v = *reinterpret_cast<const float2*>(g + (size_t)s * C + c);
            accx += v.x; accy += v.y;
        } else {
            accx += g[(size_t)s * C + c];
        }
    }

    float di = dis[i];
    if constexpr (VEC == 2) {
        float2 b = *reinterpret_cast<const float2*>(bias + c);
        float ox = di * accx + b.x;
        float oy = di * accy + b.y;
        if (RELU) { ox = fmaxf(ox, 0.f); oy = fmaxf(oy, 0.f); }
        *reinterpret_cast<float2*>(out + (size_t)i * C + c) = make_float2(ox, oy);
    } else {
        float ox = di * accx + bias[c];
        if (RELU) ox = fmaxf(ox, 0.f);
        out[(size_t)i * C + c] = ox;
    }
}

// ---------------- launch ----------------

extern "C" void kernel_launch(void* const* d_in, const int* in_sizes, int n_in,
                              void* d_out, int out_size, void* d_ws, size_t ws_size,
                              hipStream_t stream) {
    const float* x  = (const float*)d_in[0];
    const int*   ei = (const int*)d_in[1];
    const float* W1 = (const float*)d_in[2];
    const float* b1 = (const float*)d_in[3];
    const float* W2 = (const float*)d_in[4];
    const float* b2 = (const float*)d_in[5];
    const float* W3 = (const float*)d_in[6];
    const float* b3 = (const float*)d_in[7];
    float* out = (float*)d_out;

    const int n = in_sizes[0] / 64;   // 50000
    const int e = in_sizes[1] / 2;    // 800000
    const int* src = ei;
    const int* dst = ei + e;

    // workspace layout (4-byte units)
    int*   ws_i = (int*)d_ws;
    float* ws_f = (float*)d_ws;
    size_t o = 0;
    int* count   = ws_i + o; o += n;
    int* offsets = ws_i + o; o += n + 8;
    int* cursor  = ws_i + o; o += n;
    int* srcs    = ws_i + o; o += e;
    float* dis   = ws_f + o; o += n;
    o = (o + 3) & ~(size_t)3;
    float* bufA  = ws_f + o; o += (size_t)n * 128;
    float* bufB  = ws_f + o; o += (size_t)n * 128;

    const int B = 256;
    // graph preprocessing (layer-invariant, recomputed every call)
    zero_kernel<<<(n + B - 1) / B, B, 0, stream>>>(count, n);
    count_kernel<<<(e + B - 1) / B, B, 0, stream>>>(dst, count, e);
    dis_kernel<<<(n + B - 1) / B, B, 0, stream>>>(count, dis, n);
    scan_kernel<<<1, 1024, 0, stream>>>(count, offsets, cursor, n);
    fill_kernel<<<(e + B - 1) / B, B, 0, stream>>>(src, dst, cursor, srcs, e);

    dim3 agrid((n + 3) / 4);

    // layer 1: x[*,64] @ W1[64,128]  (R = 32 rows/block)
    gemm_scale<64, 128><<<(n + 31) / 32, 256, 0, stream>>>(x, W1, dis, bufA, n);
    aggregate<128, true><<<agrid, 256, 0, stream>>>(bufA, srcs, offsets, dis, b1, bufB, n);
    // layer 2: bufB[*,128] @ W2[128,128]  (R = 32)
    gemm_scale<128, 128><<<(n + 31) / 32, 256, 0, stream>>>(bufB, W2, dis, bufA, n);
    aggregate<128, true><<<agrid, 256, 0, stream>>>(bufA, srcs, offsets, dis, b2, bufB, n);
    // layer 3: bufB[*,128] @ W3[128,64]  (R = 64)
    gemm_scale<128, 64><<<(n + 63) / 64, 256, 0, stream>>>(bufB, W3, dis, bufA, n);
    aggregate<64, false><<<agrid, 256, 0, stream>>>(bufA, srcs, offsets, dis, b3, out, n);
}

// Round 3
// 381.515 us; speedup vs baseline: 1.5676x; 1.0606x over previous
//
#include <hip/hip_runtime.h>

// GCN 3-layer.
// Layer 1 (agg-first, uses linearity): a1 = dis.*(A+I_scaled)(x.*dis); h1 = relu(a1@W1+b1)
// Layer 2: g2 = (h1@W2).*dis; h2 = relu(dis.*agg(g2) + b2)
// Layer 3: g3 = (h2@W3).*dis; out = dis.*agg(g3) + b3
// dis[i] = rsqrt(1 + indegree[i])

// ---------------- graph preprocessing ----------------

__global__ void count_kernel(const int* __restrict__ dst, int* __restrict__ count, int e) {
    int i = blockIdx.x * blockDim.x + threadIdx.x;
    if (i < e) atomicAdd(&count[dst[i]], 1);
}

// single-block exclusive scan (+ dis computation): 1024 threads x 64 elements in registers
__global__ __launch_bounds__(1024) void scan_kernel(const int* __restrict__ count,
                                                    int* __restrict__ offsets,
                                                    int* __restrict__ cursor,
                                                    float* __restrict__ dis, int n) {
    constexpr int T = 64;  // elements per thread; covers n <= 65536
    __shared__ int wsum[16];
    int tid = threadIdx.x;
    int lane = tid & 63, wid = tid >> 6;
    int base = tid * T;

    int v[T];
    int tot = 0;
    if (base + T <= n) {
        #pragma unroll
        for (int j = 0; j < T; j += 4) {
            int4 c4 = *reinterpret_cast<const int4*>(count + base + j);
            v[j + 0] = tot; tot += c4.x;
            v[j + 1] = tot; tot += c4.y;
            v[j + 2] = tot; tot += c4.z;
            v[j + 3] = tot; tot += c4.w;
            float4 d4 = make_float4(rsqrtf((float)(c4.x + 1)), rsqrtf((float)(c4.y + 1)),
                                    rsqrtf((float)(c4.z + 1)), rsqrtf((float)(c4.w + 1)));
            *reinterpret_cast<float4*>(dis + base + j) = d4;
        }
    } else {
        #pragma unroll
        for (int j = 0; j < T; ++j) {
            int idx = base + j;
            int c = (idx < n) ? count[idx] : 0;
            if (idx < n) dis[idx] = rsqrtf((float)(c + 1));
            v[j] = tot; tot += c;
        }
    }

    int x = tot;
    #pragma unroll
    for (int d = 1; d < 64; d <<= 1) {
        int t = __shfl_up(x, d, 64);
        if (lane >= d) x += t;
    }
    if (lane == 63) wsum[wid] = x;
    __syncthreads();
    if (wid == 0 && lane < 16) {
        int wv = wsum[lane];
        #pragma unroll
        for (int d = 1; d < 16; d <<= 1) {
            int t = __shfl_up(wv, d, 64);
            if (lane >= d) wv += t;
        }
        wsum[lane] = wv;
    }
    __syncthreads();
    int waveExcl = (wid == 0) ? 0 : wsum[wid - 1];
    int tbase = waveExcl + (x - tot);

    if (base + T <= n) {
        #pragma unroll
        for (int j = 0; j < T; j += 4) {
            int4 o4 = make_int4(tbase + v[j], tbase + v[j + 1], tbase + v[j + 2], tbase + v[j + 3]);
            *reinterpret_cast<int4*>(offsets + base + j) = o4;
            *reinterpret_cast<int4*>(cursor + base + j) = o4;
        }
    } else {
        #pragma unroll
        for (int j = 0; j < T; ++j) {
            int idx = base + j;
            if (idx < n) { offsets[idx] = tbase + v[j]; cursor[idx] = tbase + v[j]; }
        }
    }
    if (tid == 1023) offsets[n] = tbase + tot;
}

__global__ void fill_kernel(const int* __restrict__ src, const int* __restrict__ dst,
                            int* __restrict__ cursor, int* __restrict__ srcs_sorted, int e) {
    int i = blockIdx.x * blockDim.x + threadIdx.x;
    if (i < e) {
        int d = dst[i];
        int pos = atomicAdd(&cursor[d], 1);
        srcs_sorted[pos] = src[i];
    }
}

// ---------------- vector load/store helpers ----------------

template<int V>
__device__ inline void vload(float* d, const float* __restrict__ p) {
    if constexpr (V == 2) *reinterpret_cast<float2*>(d) = *reinterpret_cast<const float2*>(p);
    else                  *reinterpret_cast<float4*>(d) = *reinterpret_cast<const float4*>(p);
}
template<int V>
__device__ inline void vstore(float* __restrict__ p, const float* d) {
    if constexpr (V == 2) *reinterpret_cast<float2*>(p) = *reinterpret_cast<const float2*>(d);
    else                  *reinterpret_cast<float4*>(p) = *reinterpret_cast<const float4*>(d);
}

// ---------------- aggregate ----------------
// out[i] = [relu]( dis[i]*( self + sum_{edges} w_s * g[s] ) [+ bias] )
// PRESCALED: g rows already carry dis[s]; else w_s = dis[s] and self scaled by dis[i].
// One wave per node, split into two 32-lane halves; each half gathers a different edge row
// (V floats per lane, V = C/32), cross-half __shfl_xor reduce at the end.

template<int C, bool RELU, bool PRESCALED, bool BIAS>
__global__ __launch_bounds__(256) void aggregate(const float* __restrict__ g,
                                                 const int* __restrict__ srcs,
                                                 const int* __restrict__ offsets,
                                                 const float* __restrict__ dis,
                                                 const float* __restrict__ bias,
                                                 float* __restrict__ out, int n) {
    constexpr int V = C / 32;
    int wid = threadIdx.x >> 6, lane = threadIdx.x & 63;
    int half = lane >> 5, cl = lane & 31;
    int i = blockIdx.x * 4 + wid;
    if (i >= n) return;
    int c = cl * V;
    float di = dis[i];

    float acc[V];
    #pragma unroll
    for (int v = 0; v < V; ++v) acc[v] = 0.f;

    if (half == 0) {
        float sf[V];
        vload<V>(sf, g + (size_t)i * C + c);
        #pragma unroll
        for (int v = 0; v < V; ++v) acc[v] = PRESCALED ? sf[v] : sf[v] * di;
    }

    int e0 = offsets[i], e1 = offsets[i + 1];
    int e = e0;
    for (; e + 4 <= e1; e += 4) {
        int sA = srcs[e + half];
        int sB = srcs[e + 2 + half];
        float lA[V], lB[V];
        vload<V>(lA, g + (size_t)sA * C + c);
        vload<V>(lB, g + (size_t)sB * C + c);
        if constexpr (!PRESCALED) {
            float wA = dis[sA], wB = dis[sB];
            #pragma unroll
            for (int v = 0; v < V; ++v) acc[v] += lA[v] * wA + lB[v] * wB;
        } else {
            #pragma unroll
            for (int v = 0; v < V; ++v) acc[v] += lA[v] + lB[v];
        }
    }
    if (e + 2 <= e1) {
        int sA = srcs[e + half];
        float lA[V];
        vload<V>(lA, g + (size_t)sA * C + c);
        float wA = 1.f;
        if constexpr (!PRESCALED) wA = dis[sA];
        #pragma unroll
        for (int v = 0; v < V; ++v) acc[v] += lA[v] * wA;
        e += 2;
    }
    if (e < e1 && half == 0) {
        int s = srcs[e];
        float lA[V];
        vload<V>(lA, g + (size_t)s * C + c);
        float wA = 1.f;
        if constexpr (!PRESCALED) wA = dis[s];
        #pragma unroll
        for (int v = 0; v < V; ++v) acc[v] += lA[v] * wA;
    }

    #pragma unroll
    for (int v = 0; v < V; ++v) acc[v] += __shfl_xor(acc[v], 32, 64);

    if (half == 0) {
        float o[V];
        #pragma unroll
        for (int v = 0; v < V; ++v) {
            float t = di * acc[v];
            if constexpr (BIAS) t += bias[c + v];
            if constexpr (RELU) t = fmaxf(t, 0.f);
            o[v] = t;
        }
        vstore<V>(out + (size_t)i * C + c, o);
    }
}

// ---------------- GEMM with epilogue ----------------
// EPI 0: out[row] = acc * aux[row]   (aux = dis, message prep)
// EPI 1: out[row] = relu(acc + aux[col])  (aux = bias)

template<int CIN, int COUT, int RPT, int EPI>
__global__ __launch_bounds__(256) void gemm_ep(const float* __restrict__ in,
                                               const float* __restrict__ W,
                                               const float* __restrict__ aux,
                                               float* __restrict__ out, int n) {
    constexpr int G = COUT / 4;
    constexpr int TY = 256 / G;
    constexpr int R = TY * RPT;
    __shared__ float wlds[CIN * COUT];
    for (int idx = threadIdx.x * 4; idx < CIN * COUT; idx += 1024)
        *reinterpret_cast<float4*>(&wlds[idx]) = *reinterpret_cast<const float4*>(&W[idx]);
    __syncthreads();

    int tx = threadIdx.x % G;
    int ty = threadIdx.x / G;
    int c0 = tx * 4;
    int rowBase = blockIdx.x * R + ty * RPT;

    int r[RPT];
    #pragma unroll
    for (int j = 0; j < RPT; ++j) r[j] = min(rowBase + j, n - 1);

    float4 acc[RPT];
    #pragma unroll
    for (int j = 0; j < RPT; ++j) acc[j] = make_float4(0.f, 0.f, 0.f, 0.f);

    #pragma unroll 2
    for (int k = 0; k < CIN; k += 4) {
        float4 w0 = *reinterpret_cast<const float4*>(&wlds[(k + 0) * COUT + c0]);
        float4 w1 = *reinterpret_cast<const float4*>(&wlds[(k + 1) * COUT + c0]);
        float4 w2 = *reinterpret_cast<const float4*>(&wlds[(k + 2) * COUT + c0]);
        float4 w3 = *reinterpret_cast<const float4*>(&wlds[(k + 3) * COUT + c0]);
        #pragma unroll
        for (int j = 0; j < RPT; ++j) {
            float4 a = *reinterpret_cast<const float4*>(in + (size_t)r[j] * CIN + k);
            acc[j].x += a.x * w0.x + a.y * w1.x + a.z * w2.x + a.w * w3.x;
            acc[j].y += a.x * w0.y + a.y * w1.y + a.z * w2.y + a.w * w3.y;
            acc[j].z += a.x * w0.z + a.y * w1.z + a.z * w2.z + a.w * w3.z;
            acc[j].w += a.x * w0.w + a.y * w1.w + a.z * w2.w + a.w * w3.w;
        }
    }

    if constexpr (EPI == 1) {
        float4 b = *reinterpret_cast<const float4*>(aux + c0);
        #pragma unroll
        for (int j = 0; j < RPT; ++j) {
            if (rowBase + j < n) {
                float4 o = make_float4(fmaxf(acc[j].x + b.x, 0.f), fmaxf(acc[j].y + b.y, 0.f),
                                       fmaxf(acc[j].z + b.z, 0.f), fmaxf(acc[j].w + b.w, 0.f));
                *reinterpret_cast<float4*>(out + (size_t)r[j] * COUT + c0) = o;
            }
        }
    } else {
        #pragma unroll
        for (int j = 0; j < RPT; ++j) {
            if (rowBase + j < n) {
                float d = aux[r[j]];
                float4 o = make_float4(acc[j].x * d, acc[j].y * d, acc[j].z * d, acc[j].w * d);
                *reinterpret_cast<float4*>(out + (size_t)r[j] * COUT + c0) = o;
            }
        }
    }
}

// ---------------- launch ----------------

extern "C" void kernel_launch(void* const* d_in, const int* in_sizes, int n_in,
                              void* d_out, int out_size, void* d_ws, size_t ws_size,
                              hipStream_t stream) {
    const float* x  = (const float*)d_in[0];
    const int*   ei = (const int*)d_in[1];
    const float* W1 = (const float*)d_in[2];
    const float* b1 = (const float*)d_in[3];
    const float* W2 = (const float*)d_in[4];
    const float* b2 = (const float*)d_in[5];
    const float* W3 = (const float*)d_in[6];
    const float* b3 = (const float*)d_in[7];
    float* out = (float*)d_out;

    const int n = in_sizes[0] / 64;   // 50000
    const int e = in_sizes[1] / 2;    // 800000
    const int* src = ei;
    const int* dst = ei + e;

    // workspace layout (4-byte units)
    int*   ws_i = (int*)d_ws;
    float* ws_f = (float*)d_ws;
    size_t o = 0;
    int* count   = ws_i + o; o += n;
    int* offsets = ws_i + o; o += n + 8;
    int* cursor  = ws_i + o; o += n;
    int* srcs    = ws_i + o; o += e;
    float* dis   = ws_f + o; o += n;
    o = (o + 3) & ~(size_t)3;
    float* bufA  = ws_f + o; o += (size_t)n * 128;
    float* bufB  = ws_f + o; o += (size_t)n * 128;

    const int B = 256;
    hipMemsetAsync(count, 0, (size_t)n * sizeof(int), stream);
    count_kernel<<<(e + B - 1) / B, B, 0, stream>>>(dst, count, e);
    scan_kernel<<<1, 1024, 0, stream>>>(count, offsets, cursor, dis, n);
    fill_kernel<<<(e + B - 1) / B, B, 0, stream>>>(src, dst, cursor, srcs, e);

    dim3 agrid((n + 3) / 4);
    dim3 ggrid((n + 63) / 64);

    // layer 1: aggregate x first (64-wide), then GEMM 64->128 with bias+relu
    aggregate<64, false, false, false><<<agrid, 256, 0, stream>>>(x, srcs, offsets, dis, nullptr, bufA, n);
    gemm_ep<64, 128, 8, 1><<<ggrid, 256, 0, stream>>>(bufA, W1, b1, bufB, n);
    // layer 2: g2 = (h1@W2)*dis ; h2 = relu(dis*agg(g2)+b2)
    gemm_ep<128, 128, 8, 0><<<ggrid, 256, 0, stream>>>(bufB, W2, dis, bufA, n);
    aggregate<128, true, true, true><<<agrid, 256, 0, stream>>>(bufA, srcs, offsets, dis, b2, bufB, n);
    // layer 3: g3 = (h2@W3)*dis ; out = dis*agg(g3)+b3
    gemm_ep<128, 64, 4, 0><<<ggrid, 256, 0, stream>>>(bufB, W3, dis, bufA, n);
    aggregate<64, false, true, true><<<agrid, 256, 0, stream>>>(bufA, srcs, offsets, dis, b3, out, n);
}

// Round 4
// 368.371 us; speedup vs baseline: 1.6235x; 1.0357x over previous
//
#include <hip/hip_runtime.h>

// GCN 3-layer.
// Layer 1 (agg-first, uses linearity): a1 = dis.*(A+I_scaled)(x.*dis); h1 = relu(a1@W1+b1)
// Layer 2: g2 = (h1@W2).*dis; h2 = relu(dis.*agg(g2) + b2)
// Layer 3: g3 = (h2@W3).*dis; out = dis.*agg(g3) + b3
// dis[i] = rsqrt(1 + indegree[i])

// ---------------- graph preprocessing ----------------

__global__ void count_kernel(const int* __restrict__ dst, int* __restrict__ count, int e) {
    int i = blockIdx.x * blockDim.x + threadIdx.x;
    if (i < e) atomicAdd(&count[dst[i]], 1);
}

// single-block exclusive scan (+ dis computation): 1024 threads x 64 elements in registers
__global__ __launch_bounds__(1024) void scan_kernel(const int* __restrict__ count,
                                                    int* __restrict__ offsets,
                                                    int* __restrict__ cursor,
                                                    float* __restrict__ dis, int n) {
    constexpr int T = 64;  // elements per thread; covers n <= 65536
    __shared__ int wsum[16];
    int tid = threadIdx.x;
    int lane = tid & 63, wid = tid >> 6;
    int base = tid * T;

    int v[T];
    int tot = 0;
    if (base + T <= n) {
        #pragma unroll
        for (int j = 0; j < T; j += 4) {
            int4 c4 = *reinterpret_cast<const int4*>(count + base + j);
            v[j + 0] = tot; tot += c4.x;
            v[j + 1] = tot; tot += c4.y;
            v[j + 2] = tot; tot += c4.z;
            v[j + 3] = tot; tot += c4.w;
            float4 d4 = make_float4(rsqrtf((float)(c4.x + 1)), rsqrtf((float)(c4.y + 1)),
                                    rsqrtf((float)(c4.z + 1)), rsqrtf((float)(c4.w + 1)));
            *reinterpret_cast<float4*>(dis + base + j) = d4;
        }
    } else {
        #pragma unroll
        for (int j = 0; j < T; ++j) {
            int idx = base + j;
            int c = (idx < n) ? count[idx] : 0;
            if (idx < n) dis[idx] = rsqrtf((float)(c + 1));
            v[j] = tot; tot += c;
        }
    }

    int x = tot;
    #pragma unroll
    for (int d = 1; d < 64; d <<= 1) {
        int t = __shfl_up(x, d, 64);
        if (lane >= d) x += t;
    }
    if (lane == 63) wsum[wid] = x;
    __syncthreads();
    if (wid == 0 && lane < 16) {
        int wv = wsum[lane];
        #pragma unroll
        for (int d = 1; d < 16; d <<= 1) {
            int t = __shfl_up(wv, d, 64);
            if (lane >= d) wv += t;
        }
        wsum[lane] = wv;
    }
    __syncthreads();
    int waveExcl = (wid == 0) ? 0 : wsum[wid - 1];
    int tbase = waveExcl + (x - tot);

    if (base + T <= n) {
        #pragma unroll
        for (int j = 0; j < T; j += 4) {
            int4 o4 = make_int4(tbase + v[j], tbase + v[j + 1], tbase + v[j + 2], tbase + v[j + 3]);
            *reinterpret_cast<int4*>(offsets + base + j) = o4;
            *reinterpret_cast<int4*>(cursor + base + j) = o4;
        }
    } else {
        #pragma unroll
        for (int j = 0; j < T; ++j) {
            int idx = base + j;
            if (idx < n) { offsets[idx] = tbase + v[j]; cursor[idx] = tbase + v[j]; }
        }
    }
    if (tid == 1023) offsets[n] = tbase + tot;
}

__global__ void fill_kernel(const int* __restrict__ src, const int* __restrict__ dst,
                            int* __restrict__ cursor, int* __restrict__ srcs_sorted, int e) {
    int i = blockIdx.x * blockDim.x + threadIdx.x;
    if (i < e) {
        int d = dst[i];
        int pos = atomicAdd(&cursor[d], 1);
        srcs_sorted[pos] = src[i];
    }
}

// ---------------- aggregate ----------------
// out[i] = [relu]( dis[i]*( self + sum_{edges} w_s * g[s] ) [+ bias] )
// PRESCALED: g rows already carry dis[s]; else w_s = dis[s], self scaled by dis[i].
// C=128: wave = 2 halves x 32 lanes (float4/lane), 4 edges in flight per half.
// C=64 : wave = 4 groups x 16 lanes (float4/lane), 2 edges in flight per group.

template<int C, bool RELU, bool PRESCALED, bool BIAS>
__global__ __launch_bounds__(256) void aggregate(const float* __restrict__ g,
                                                 const int* __restrict__ srcs,
                                                 const int* __restrict__ offsets,
                                                 const float* __restrict__ dis,
                                                 const float* __restrict__ bias,
                                                 float* __restrict__ out, int n) {
    int wid = threadIdx.x >> 6, lane = threadIdx.x & 63;
    int i = blockIdx.x * 4 + wid;
    if (i >= n) return;
    float di = dis[i];
    int e0 = offsets[i], e1 = offsets[i + 1];
    int e = e0;

    if constexpr (C == 128) {
        int half = lane >> 5, cl = lane & 31;
        int c = cl * 4;
        const float* gc = g + c;
        float4 a0 = make_float4(0.f, 0.f, 0.f, 0.f), a1 = a0, a2 = a0, a3 = a0;

        if (half == 0) {
            float4 sf = *reinterpret_cast<const float4*>(gc + (size_t)i * C);
            float w = PRESCALED ? 1.f : di;
            a0 = make_float4(sf.x * w, sf.y * w, sf.z * w, sf.w * w);
        }

        for (; e + 8 <= e1; e += 8) {
            int s0 = srcs[e + half], s1 = srcs[e + 2 + half];
            int s2 = srcs[e + 4 + half], s3 = srcs[e + 6 + half];
            float4 l0 = *reinterpret_cast<const float4*>(gc + (size_t)s0 * C);
            float4 l1 = *reinterpret_cast<const float4*>(gc + (size_t)s1 * C);
            float4 l2 = *reinterpret_cast<const float4*>(gc + (size_t)s2 * C);
            float4 l3 = *reinterpret_cast<const float4*>(gc + (size_t)s3 * C);
            a0.x += l0.x; a0.y += l0.y; a0.z += l0.z; a0.w += l0.w;
            a1.x += l1.x; a1.y += l1.y; a1.z += l1.z; a1.w += l1.w;
            a2.x += l2.x; a2.y += l2.y; a2.z += l2.z; a2.w += l2.w;
            a3.x += l3.x; a3.y += l3.y; a3.z += l3.z; a3.w += l3.w;
        }
        if (e + 4 <= e1) {
            int s0 = srcs[e + half], s1 = srcs[e + 2 + half];
            float4 l0 = *reinterpret_cast<const float4*>(gc + (size_t)s0 * C);
            float4 l1 = *reinterpret_cast<const float4*>(gc + (size_t)s1 * C);
            a0.x += l0.x; a0.y += l0.y; a0.z += l0.z; a0.w += l0.w;
            a1.x += l1.x; a1.y += l1.y; a1.z += l1.z; a1.w += l1.w;
            e += 4;
        }
        if (e + 2 <= e1) {
            int s0 = srcs[e + half];
            float4 l0 = *reinterpret_cast<const float4*>(gc + (size_t)s0 * C);
            a2.x += l0.x; a2.y += l0.y; a2.z += l0.z; a2.w += l0.w;
            e += 2;
        }
        if (e < e1 && half == 0) {
            int s0 = srcs[e];
            float4 l0 = *reinterpret_cast<const float4*>(gc + (size_t)s0 * C);
            a3.x += l0.x; a3.y += l0.y; a3.z += l0.z; a3.w += l0.w;
        }

        float4 acc = make_float4((a0.x + a1.x) + (a2.x + a3.x), (a0.y + a1.y) + (a2.y + a3.y),
                                 (a0.z + a1.z) + (a2.z + a3.z), (a0.w + a1.w) + (a2.w + a3.w));
        acc.x += __shfl_xor(acc.x, 32, 64);
        acc.y += __shfl_xor(acc.y, 32, 64);
        acc.z += __shfl_xor(acc.z, 32, 64);
        acc.w += __shfl_xor(acc.w, 32, 64);

        if (half == 0) {
            float4 o;
            o.x = di * acc.x; o.y = di * acc.y; o.z = di * acc.z; o.w = di * acc.w;
            if constexpr (BIAS) {
                float4 b = *reinterpret_cast<const float4*>(bias + c);
                o.x += b.x; o.y += b.y; o.z += b.z; o.w += b.w;
            }
            if constexpr (RELU) {
                o.x = fmaxf(o.x, 0.f); o.y = fmaxf(o.y, 0.f);
                o.z = fmaxf(o.z, 0.f); o.w = fmaxf(o.w, 0.f);
            }
            *reinterpret_cast<float4*>(out + (size_t)i * C + c) = o;
        }
    } else {  // C == 64
        int grp = lane >> 4, cl = lane & 15;
        int c = cl * 4;
        const float* gc = g + c;
        float4 a0 = make_float4(0.f, 0.f, 0.f, 0.f), a1 = a0;

        if (grp == 0) {
            float4 sf = *reinterpret_cast<const float4*>(gc + (size_t)i * C);
            float w = PRESCALED ? 1.f : di;
            a0 = make_float4(sf.x * w, sf.y * w, sf.z * w, sf.w * w);
        }

        for (; e + 8 <= e1; e += 8) {
            int s0 = srcs[e + grp], s1 = srcs[e + 4 + grp];
            float4 l0 = *reinterpret_cast<const float4*>(gc + (size_t)s0 * C);
            float4 l1 = *reinterpret_cast<const float4*>(gc + (size_t)s1 * C);
            float w0 = 1.f, w1 = 1.f;
            if constexpr (!PRESCALED) { w0 = dis[s0]; w1 = dis[s1]; }
            a0.x += l0.x * w0; a0.y += l0.y * w0; a0.z += l0.z * w0; a0.w += l0.w * w0;
            a1.x += l1.x * w1; a1.y += l1.y * w1; a1.z += l1.z * w1; a1.w += l1.w * w1;
        }
        if (e + 4 <= e1) {
            int s0 = srcs[e + grp];
            float4 l0 = *reinterpret_cast<const float4*>(gc + (size_t)s0 * C);
            float w0 = 1.f;
            if constexpr (!PRESCALED) w0 = dis[s0];
            a0.x += l0.x * w0; a0.y += l0.y * w0; a0.z += l0.z * w0; a0.w += l0.w * w0;
            e += 4;
        }
        int rem = e1 - e;  // 0..3
        if (grp < rem) {
            int s0 = srcs[e + grp];
            float4 l0 = *reinterpret_cast<const float4*>(gc + (size_t)s0 * C);
            float w0 = 1.f;
            if constexpr (!PRESCALED) w0 = dis[s0];
            a1.x += l0.x * w0; a1.y += l0.y * w0; a1.z += l0.z * w0; a1.w += l0.w * w0;
        }

        float4 acc = make_float4(a0.x + a1.x, a0.y + a1.y, a0.z + a1.z, a0.w + a1.w);
        #pragma unroll
        for (int d = 16; d <= 32; d <<= 1) {
            acc.x += __shfl_xor(acc.x, d, 64);
            acc.y += __shfl_xor(acc.y, d, 64);
            acc.z += __shfl_xor(acc.z, d, 64);
            acc.w += __shfl_xor(acc.w, d, 64);
        }

        if (grp == 0) {
            float4 o;
            o.x = di * acc.x; o.y = di * acc.y; o.z = di * acc.z; o.w = di * acc.w;
            if constexpr (BIAS) {
                float4 b = *reinterpret_cast<const float4*>(bias + c);
                o.x += b.x; o.y += b.y; o.z += b.z; o.w += b.w;
            }
            if constexpr (RELU) {
                o.x = fmaxf(o.x, 0.f); o.y = fmaxf(o.y, 0.f);
                o.z = fmaxf(o.z, 0.f); o.w = fmaxf(o.w, 0.f);
            }
            *reinterpret_cast<float4*>(out + (size_t)i * C + c) = o;
        }
    }
}

// ---------------- GEMM with epilogue ----------------
// EPI 0: out[row] = acc * aux[row]   (aux = dis, message prep)
// EPI 1: out[row] = relu(acc + aux[col])  (aux = bias)

template<int CIN, int COUT, int RPT, int EPI>
__global__ __launch_bounds__(256) void gemm_ep(const float* __restrict__ in,
                                               const float* __restrict__ W,
                                               const float* __restrict__ aux,
                                               float* __restrict__ out, int n) {
    constexpr int G = COUT / 4;
    constexpr int TY = 256 / G;
    constexpr int R = TY * RPT;
    __shared__ float wlds[CIN * COUT];
    for (int idx = threadIdx.x * 4; idx < CIN * COUT; idx += 1024)
        *reinterpret_cast<float4*>(&wlds[idx]) = *reinterpret_cast<const float4*>(&W[idx]);
    __syncthreads();

    int tx = threadIdx.x % G;
    int ty = threadIdx.x / G;
    int c0 = tx * 4;
    int rowBase = blockIdx.x * R + ty * RPT;

    int r[RPT];
    #pragma unroll
    for (int j = 0; j < RPT; ++j) r[j] = min(rowBase + j, n - 1);

    float4 acc[RPT];
    #pragma unroll
    for (int j = 0; j < RPT; ++j) acc[j] = make_float4(0.f, 0.f, 0.f, 0.f);

    #pragma unroll 2
    for (int k = 0; k < CIN; k += 4) {
        float4 w0 = *reinterpret_cast<const float4*>(&wlds[(k + 0) * COUT + c0]);
        float4 w1 = *reinterpret_cast<const float4*>(&wlds[(k + 1) * COUT + c0]);
        float4 w2 = *reinterpret_cast<const float4*>(&wlds[(k + 2) * COUT + c0]);
        float4 w3 = *reinterpret_cast<const float4*>(&wlds[(k + 3) * COUT + c0]);
        #pragma unroll
        for (int j = 0; j < RPT; ++j) {
            float4 a = *reinterpret_cast<const float4*>(in + (size_t)r[j] * CIN + k);
            acc[j].x += a.x * w0.x + a.y * w1.x + a.z * w2.x + a.w * w3.x;
            acc[j].y += a.x * w0.y + a.y * w1.y + a.z * w2.y + a.w * w3.y;
            acc[j].z += a.x * w0.z + a.y * w1.z + a.z * w2.z + a.w * w3.z;
            acc[j].w += a.x * w0.w + a.y * w1.w + a.z * w2.w + a.w * w3.w;
        }
    }

    if constexpr (EPI == 1) {
        float4 b = *reinterpret_cast<const float4*>(aux + c0);
        #pragma unroll
        for (int j = 0; j < RPT; ++j) {
            if (rowBase + j < n) {
                float4 o = make_float4(fmaxf(acc[j].x + b.x, 0.f), fmaxf(acc[j].y + b.y, 0.f),
                                       fmaxf(acc[j].z + b.z, 0.f), fmaxf(acc[j].w + b.w, 0.f));
                *reinterpret_cast<float4*>(out + (size_t)r[j] * COUT + c0) = o;
            }
        }
    } else {
        #pragma unroll
        for (int j = 0; j < RPT; ++j) {
            if (rowBase + j < n) {
                float d = aux[r[j]];
                float4 o = make_float4(acc[j].x * d, acc[j].y * d, acc[j].z * d, acc[j].w * d);
                *reinterpret_cast<float4*>(out + (size_t)r[j] * COUT + c0) = o;
            }
        }
    }
}

// ---------------- launch ----------------

extern "C" void kernel_launch(void* const* d_in, const int* in_sizes, int n_in,
                              void* d_out, int out_size, void* d_ws, size_t ws_size,
                              hipStream_t stream) {
    const float* x  = (const float*)d_in[0];
    const int*   ei = (const int*)d_in[1];
    const float* W1 = (const float*)d_in[2];
    const float* b1 = (const float*)d_in[3];
    const float* W2 = (const float*)d_in[4];
    const float* b2 = (const float*)d_in[5];
    const float* W3 = (const float*)d_in[6];
    const float* b3 = (const float*)d_in[7];
    float* out = (float*)d_out;

    const int n = in_sizes[0] / 64;   // 50000
    const int e = in_sizes[1] / 2;    // 800000
    const int* src = ei;
    const int* dst = ei + e;

    // workspace layout (4-byte units)
    int*   ws_i = (int*)d_ws;
    float* ws_f = (float*)d_ws;
    size_t o = 0;
    int* count   = ws_i + o; o += n;
    int* offsets = ws_i + o; o += n + 8;
    int* cursor  = ws_i + o; o += n;
    int* srcs    = ws_i + o; o += e;
    float* dis   = ws_f + o; o += n;
    o = (o + 3) & ~(size_t)3;
    float* bufA  = ws_f + o; o += (size_t)n * 128;
    float* bufB  = ws_f + o; o += (size_t)n * 128;

    const int B = 256;
    hipMemsetAsync(count, 0, (size_t)n * sizeof(int), stream);
    count_kernel<<<(e + B - 1) / B, B, 0, stream>>>(dst, count, e);
    scan_kernel<<<1, 1024, 0, stream>>>(count, offsets, cursor, dis, n);
    fill_kernel<<<(e + B - 1) / B, B, 0, stream>>>(src, dst, cursor, srcs, e);

    dim3 agrid((n + 3) / 4);
    dim3 ggrid((n + 63) / 64);

    // layer 1: aggregate x first (64-wide), then GEMM 64->128 with bias+relu
    aggregate<64, false, false, false><<<agrid, 256, 0, stream>>>(x, srcs, offsets, dis, nullptr, bufA, n);
    gemm_ep<64, 128, 8, 1><<<ggrid, 256, 0, stream>>>(bufA, W1, b1, bufB, n);
    // layer 2: g2 = (h1@W2)*dis ; h2 = relu(dis*agg(g2)+b2)
    gemm_ep<128, 128, 8, 0><<<ggrid, 256, 0, stream>>>(bufB, W2, dis, bufA, n);
    aggregate<128, true, true, true><<<agrid, 256, 0, stream>>>(bufA, srcs, offsets, dis, b2, bufB, n);
    // layer 3: g3 = (h2@W3)*dis ; out = dis*agg(g3)+b3
    gemm_ep<128, 64, 4, 0><<<ggrid, 256, 0, stream>>>(bufB, W3, dis, bufA, n);
    aggregate<64, false, true, true><<<agrid, 256, 0, stream>>>(bufA, srcs, offsets, dis, b3, out, n);
}